// Round 1
// baseline (353.567 us; speedup 1.0000x reference)
//
#include <hip/hip_runtime.h>
#include <hip/hip_bf16.h>

typedef __attribute__((ext_vector_type(8))) short short8;
typedef __attribute__((ext_vector_type(4))) float f32x4;
typedef __attribute__((ext_vector_type(2))) float f32x2;

#define NN 100000
#define NE 3200000

__device__ __forceinline__ short f2bf(float f) {
  __hip_bfloat16 h = __float2bfloat16(f);
  return *reinterpret_cast<short*>(&h);
}

__device__ __forceinline__ f32x4 mfma16(short8 a, short8 b, f32x4 c) {
  return __builtin_amdgcn_mfma_f32_16x16x32_bf16(a, b, c, 0, 0, 0);
}

// Per-wave tile: 16 edges. A-frag: lane holds row (l&15), k=(l>>4)*8+j.
// B-frag: lane holds col (l&15), k=(l>>4)*8+j. D: row=(l>>4)*4+r, col=(l&15).
__global__ void __launch_bounds__(256) mpn_main(
    const float* __restrict__ x_node,
    const float* __restrict__ x_edge,
    const int*   __restrict__ srcp,
    const int*   __restrict__ dstp,
    const int*   __restrict__ bmp,
    const float* __restrict__ Wn1, const float* __restrict__ bn1,
    const float* __restrict__ Wn2, const float* __restrict__ bn2,
    const float* __restrict__ We1, const float* __restrict__ be1,
    const float* __restrict__ We2, const float* __restrict__ be2,
    float* __restrict__ out_nm,
    float* __restrict__ out_em)
{
  // per-wave private transpose tiles (strides padded for bank spread / 16B align)
  __shared__ short lds_h1[4][16][40];  // h1: 16 edges x 32 neurons (bf16), row stride 80B
  __shared__ float lds_em[4][16][12];  // em: 16 edges x 6 (+pad zeros), row stride 48B
  __shared__ short lds_h2[4][16][72];  // h2: 16 edges x 64 neurons (bf16), row stride 144B

  const int tid  = threadIdx.x;
  const int wid  = tid >> 6;
  const int lane = tid & 63;
  const int col  = lane & 15;
  const int kg   = lane >> 4;

  // zero em tile so pad cols (6,7) read as 0
  for (int i = lane; i < 16 * 12; i += 64)
    ((float*)lds_em[wid])[i] = 0.f;

  // ---- resident bf16 weight B-fragments (one-time) ----
  auto ldb = [&](const float* W, int K, int N, int kc, int nt) {
    int n  = nt * 16 + col;
    int k0 = kc * 32 + kg * 8;
    short8 r;
#pragma unroll
    for (int j = 0; j < 8; ++j) {
      int k = k0 + j;
      float v = (k < K && n < N) ? W[k * N + n] : 0.f;
      r[j] = f2bf(v);
    }
    return r;
  };

  short8 B_e1[3][2], B_n1[2][4], B_n2[2][2], B_e2;
#pragma unroll
  for (int kc = 0; kc < 3; ++kc)
#pragma unroll
    for (int nt = 0; nt < 2; ++nt) B_e1[kc][nt] = ldb(We1, 70, 32, kc, nt);
  B_e2 = ldb(We2, 32, 6, 0, 0);
#pragma unroll
  for (int kc = 0; kc < 2; ++kc)
#pragma unroll
    for (int nt = 0; nt < 4; ++nt) B_n1[kc][nt] = ldb(Wn1, 38, 64, kc, nt);
#pragma unroll
  for (int kc = 0; kc < 2; ++kc)
#pragma unroll
    for (int nt = 0; nt < 2; ++nt) B_n2[kc][nt] = ldb(Wn2, 64, 32, kc, nt);

  float bias_e1[2], bias_n1[4], bias_n2[2], bias_e2;
  bias_e1[0] = be1[col];      bias_e1[1] = be1[16 + col];
  bias_e2    = (col < 6) ? be2[col] : 0.f;
#pragma unroll
  for (int nt = 0; nt < 4; ++nt) bias_n1[nt] = bn1[nt * 16 + col];
  bias_n2[0] = bn2[col];      bias_n2[1] = bn2[16 + col];

  const int ntiles = NE / 16;
  const int gw = blockIdx.x * 4 + wid;
  const int nw = gridDim.x * 4;

  for (int t = gw; t < ntiles; t += nw) {
    const int eb = t * 16;
    const int e  = eb + col;
    const int s  = srcp[e];
    const int d  = dstp[e];
    const bool back = bmp[e] != 0;

    // gather node features in A-fragment layout
    const float* ps = x_node + (long)s * 32 + kg * 8;
    const float* pd = x_node + (long)d * 32 + kg * 8;
    f32x4 s0 = *(const f32x4*)ps, s1 = *(const f32x4*)(ps + 4);
    f32x4 d0 = *(const f32x4*)pd, d1 = *(const f32x4*)(pd + 4);
    short8 XS, XD;
#pragma unroll
    for (int j = 0; j < 4; ++j) {
      XS[j] = f2bf(s0[j]); XS[4 + j] = f2bf(s1[j]);
      XD[j] = f2bf(d0[j]); XD[4 + j] = f2bf(d1[j]);
    }
    short8 AE = {0, 0, 0, 0, 0, 0, 0, 0};
    if (kg == 0) {  // k=64..69 are the 6 edge feats, rest pad
      const float* pe = x_edge + (long)e * 6;
      f32x2 e0 = *(const f32x2*)pe;
      f32x2 e1 = *(const f32x2*)(pe + 2);
      f32x2 e2 = *(const f32x2*)(pe + 4);
      AE[0] = f2bf(e0[0]); AE[1] = f2bf(e0[1]);
      AE[2] = f2bf(e1[0]); AE[3] = f2bf(e1[1]);
      AE[4] = f2bf(e2[0]); AE[5] = f2bf(e2[1]);
    }
    short8 Aa = back ? XD : XS;   // per-lane (per-edge-row) select
    short8 Ab = back ? XS : XD;

    // ---- edge MLP layer 1: h1 = relu([a|b|xe] @ We1 + be1) ----
    f32x4 a0 = {bias_e1[0], bias_e1[0], bias_e1[0], bias_e1[0]};
    f32x4 a1 = {bias_e1[1], bias_e1[1], bias_e1[1], bias_e1[1]};
    a0 = mfma16(Aa, B_e1[0][0], a0);
    a0 = mfma16(Ab, B_e1[1][0], a0);
    a0 = mfma16(AE, B_e1[2][0], a0);
    a1 = mfma16(Aa, B_e1[0][1], a1);
    a1 = mfma16(Ab, B_e1[1][1], a1);
    a1 = mfma16(AE, B_e1[2][1], a1);

    // D-layout -> A-layout via LDS (relu + bf16 on the way)
#pragma unroll
    for (int r = 0; r < 4; ++r) {
      lds_h1[wid][kg * 4 + r][col]      = f2bf(fmaxf(a0[r], 0.f));
      lds_h1[wid][kg * 4 + r][16 + col] = f2bf(fmaxf(a1[r], 0.f));
    }
    short8 Ah1 = *(const short8*)&lds_h1[wid][col][kg * 8];

    // ---- edge MLP layer 2: em = h1 @ We2 + be2 (cols 0..5 valid) ----
    f32x4 ae2 = {bias_e2, bias_e2, bias_e2, bias_e2};
    ae2 = mfma16(Ah1, B_e2, ae2);

    if (col < 6) {
#pragma unroll
      for (int r = 0; r < 4; ++r) {
        int row = kg * 4 + r;
        float v = ae2[r];
        out_em[(long)(eb + row) * 6 + col] = v;
        lds_em[wid][row][col] = v;
      }
    }
    short8 Aem = {0, 0, 0, 0, 0, 0, 0, 0};
    if (kg == 0) {  // k=32..39 of feat_n: em[0..5] + 2 pad zeros
      f32x4 u0 = *(const f32x4*)&lds_em[wid][col][0];
      f32x4 u1 = *(const f32x4*)&lds_em[wid][col][4];
      Aem[0] = f2bf(u0[0]); Aem[1] = f2bf(u0[1]);
      Aem[2] = f2bf(u0[2]); Aem[3] = f2bf(u0[3]);
      Aem[4] = f2bf(u1[0]); Aem[5] = f2bf(u1[1]);
      Aem[6] = f2bf(u1[2]); Aem[7] = f2bf(u1[3]);  // zeros
    }

    // ---- node MLP layer 1: h2 = relu([xd|em] @ Wn1 + bn1) ----
    f32x4 an[4];
#pragma unroll
    for (int nt = 0; nt < 4; ++nt) {
      an[nt] = (f32x4){bias_n1[nt], bias_n1[nt], bias_n1[nt], bias_n1[nt]};
      an[nt] = mfma16(XD,  B_n1[0][nt], an[nt]);
      an[nt] = mfma16(Aem, B_n1[1][nt], an[nt]);
    }
#pragma unroll
    for (int nt = 0; nt < 4; ++nt)
#pragma unroll
      for (int r = 0; r < 4; ++r)
        lds_h2[wid][kg * 4 + r][nt * 16 + col] = f2bf(fmaxf(an[nt][r], 0.f));
    short8 Ah2a = *(const short8*)&lds_h2[wid][col][kg * 8];
    short8 Ah2b = *(const short8*)&lds_h2[wid][col][32 + kg * 8];

    // ---- node MLP layer 2: msg = h2 @ Wn2 + bn2 ----
    f32x4 am0 = {bias_n2[0], bias_n2[0], bias_n2[0], bias_n2[0]};
    f32x4 am1 = {bias_n2[1], bias_n2[1], bias_n2[1], bias_n2[1]};
    am0 = mfma16(Ah2a, B_n2[0][0], am0);
    am0 = mfma16(Ah2b, B_n2[1][0], am0);
    am1 = mfma16(Ah2a, B_n2[0][1], am1);
    am1 = mfma16(Ah2b, B_n2[1][1], am1);

    // ---- scatter-add into nm ----
#pragma unroll
    for (int r = 0; r < 4; ++r) {
      int de = dstp[eb + kg * 4 + r];
      float* basep = out_nm + (long)de * 32 + col;
      unsafeAtomicAdd(basep,      am0[r]);
      unsafeAtomicAdd(basep + 16, am1[r]);
    }
  }
}

extern "C" void kernel_launch(void* const* d_in, const int* in_sizes, int n_in,
                              void* d_out, int out_size, void* d_ws, size_t ws_size,
                              hipStream_t stream) {
  const float* x_node = (const float*)d_in[0];
  const float* x_edge = (const float*)d_in[1];
  const int*   src    = (const int*)d_in[2];
  const int*   dst    = (const int*)d_in[3];
  const int*   bm     = (const int*)d_in[4];
  const float* Wn1 = (const float*)d_in[5];  const float* bn1 = (const float*)d_in[6];
  const float* Wn2 = (const float*)d_in[7];  const float* bn2 = (const float*)d_in[8];
  const float* We1 = (const float*)d_in[9];  const float* be1 = (const float*)d_in[10];
  const float* We2 = (const float*)d_in[11]; const float* be2 = (const float*)d_in[12];
  float* out_nm = (float*)d_out;
  float* out_em = out_nm + (size_t)NN * 32;

  // nm is accumulated with atomics -> must start at zero every call
  hipMemsetAsync(out_nm, 0, (size_t)NN * 32 * sizeof(float), stream);
  mpn_main<<<1024, 256, 0, stream>>>(x_node, x_edge, src, dst, bm,
                                     Wn1, bn1, Wn2, bn2, We1, be1, We2, be2,
                                     out_nm, out_em);
}